// Round 17
// baseline (22.829 us; speedup 1.0000x reference)
//
#include <hip/hip_runtime.h>
#include <math.h>

#define NIMG 24        // B*C = 8*3
#define H    256
#define W    256
#define NPIX (H * W)
#define NROWS (NIMG * H)          // 6144
#define CPB  16                   // columns per K2 tile
#define NBLK2 (NIMG * (W / CPB))  // 384
#define LDP2 17                   // padded LDS row stride (floats)
#define BIGI 1000000
#define CAPS 1024                 // int16 sentinel for capped g (=1e6)

// ---------------------------------------------------------------------------
// K1: 384 blocks x 256 thr (4 waves x 4 rows = 16 rows/block) — r16 lesson:
// 192 blocks left 25% of CUs idle; 384 gives 1.5 blocks/CU. The 4 row
// loads are HOISTED ahead of the 4 process steps (independent int4 loads
// overlap ~3 of 4 cold-load latencies in-wave). Ballot-based O(1) row EDT
// (r11-validated bit-exact), int16 output (r13-validated: +-g in [1,256],
// sentinel +-1024 for capped rows). Thread (0,0) zeroes out[0] — published
// to K2's atomics by the node boundary.
// ---------------------------------------------------------------------------
__global__ __launch_bounds__(256)
void edt_rows_kernel(const int* __restrict__ tgt,
                     short* __restrict__ f,
                     float* __restrict__ out) {
    if (blockIdx.x == 0 && threadIdx.x == 0) out[0] = 0.0f;

    const int lane = threadIdx.x & 63;
    const int wid  = threadIdx.x >> 6;        // 0..3
    const int gw   = blockIdx.x * 4 + wid;    // 0..1535
    const int c0   = lane << 2;

    // hoisted loads: 4 independent row reads
    int4 tvs[4];
#pragma unroll
    for (int s = 0; s < 4; ++s)
        tvs[s] = ((const int4*)(tgt + (((gw << 2) + s) << 8)))[lane];

#pragma unroll
    for (int s = 0; s < 4; ++s) {
        const int row = (gw << 2) + s;
        const int4 tv = tvs[s];

        // class-change flags (index 0 has no predecessor -> false)
        const int prevw = __shfl_up(tv.w, 1, 64);
        const bool ch0 = (lane > 0) && ((tv.x != 0) != (prevw != 0));
        const bool ch1 = (tv.y != 0) != (tv.x != 0);
        const bool ch2 = (tv.z != 0) != (tv.y != 0);
        const bool ch3 = (tv.w != 0) != (tv.z != 0);

        const int a0 = ch0 ? c0     : -BIGI;
        const int a1 = ch1 ? c0 + 1 : a0;
        const int a2 = ch2 ? c0 + 2 : a1;
        const int a3 = ch3 ? c0 + 3 : a2;     // lane's last change (or -BIGI)
        const int rb3 = ch3 ? c0 + 3 : BIGI;
        const int rb2 = ch2 ? c0 + 2 : rb3;
        const int rb1 = ch1 ? c0 + 1 : rb2;
        const int rb0 = ch0 ? c0     : rb1;   // lane's first change (or BIGI)

        const unsigned long long mask = __ballot(ch0 | ch1 | ch2 | ch3);
        const unsigned long long lowm = mask & ((1ULL << lane) - 1ULL);
        const unsigned long long him  = (lane < 63) ? (mask >> (lane + 1)) : 0ULL;

        const int plane = 63 - __builtin_clzll(lowm | 1ULL);
        const int sh_a  = __shfl(a3, plane & 63, 64);
        const int ex    = (lowm != 0ULL) ? sh_a : -BIGI;   // last change < c0

        const int qlane = lane + 1 +
            (int)__builtin_ctzll(him | 0x8000000000000000ULL);
        const int sh_r  = __shfl(rb0, qlane & 63, 64);
        const int exr   = (him != 0ULL) ? sh_r : BIGI;     // first change > c3

        const int s0 = (ex > a0) ? ex : a0;
        const int s1 = (ex > a1) ? ex : a1;
        const int s2 = (ex > a2) ? ex : a2;
        const int s3 = (ex > a3) ? ex : a3;
        const int n0 = (rb1 < exr) ? rb1 : exr;
        const int n1 = (rb2 < exr) ? rb2 : exr;
        const int n2 = (rb3 < exr) ? rb3 : exr;
        const int n3 = exr;

        auto gcalc = [](int c, int ss, int nn) -> int {
            int dp = c - ss + 1;
            int dn = nn - c;
            int g = dp < dn ? dp : dn;
            return (g < BIGI) ? g : CAPS;     // encode cap as sentinel
        };
        const int g0 = gcalc(c0,     s0, n0);
        const int g1 = gcalc(c0 + 1, s1, n1);
        const int g2 = gcalc(c0 + 2, s2, n2);
        const int g3 = gcalc(c0 + 3, s3, n3);

        short4 o;
        o.x = (short)((tv.x != 0) ? g0 : -g0);
        o.y = (short)((tv.y != 0) ? g1 : -g1);
        o.z = (short)((tv.z != 0) ? g2 : -g2);
        o.w = (short)((tv.w != 0) ? g3 : -g3);
        ((short4*)(f + (row << 8)))[lane] = o;
    }
}

// ---------------------------------------------------------------------------
// K2: 384 blocks x 512 thr, tile = (img, 16-col group) — 1.5 blocks/CU
// (r16 lesson: 192 blocks idled 25% of CUs). Stage one int4 (8 shorts) per
// thread, decode (sentinel +-1024 -> +-1e6f; r13-validated) into padded
// LDS. Empty-mask flag from cap markers (r10/r11-validated). PRED PREFETCH
// (r17): the 8 per-thread pred loads are issued into registers BEFORE the
// window loop so their latency hides under LDS compute. Window-bounded
// exact min-plus (minimizer satisfies |i-k| <= g[i] since k=i gives
// g[i]^2; extra k provably never changes the min; all finite terms exact
// fp32 ints -> bitwise equal to reference). 8 px/thread, 8-wave fixed-order
// double reduction; fp32 atomic finalize (r16-validated: bare consumer-side
// RMW, no fences; rounding ~1e-8 << 1.2e-5 threshold).
// ---------------------------------------------------------------------------
__global__ __launch_bounds__(512)
void edt_cols_kernel(const short* __restrict__ f,
                     const float* __restrict__ pred,
                     float* __restrict__ out) {
    const int bid  = blockIdx.x;          // img*16 + grp
    const int img  = bid >> 4;
    const int j0   = (bid & 15) << 4;
    const int t    = threadIdx.x;
    const int lane = t & 63;
    const int wid  = t >> 6;

    __shared__ float sf[H][LDP2];         // 17.4 KB decoded f tile
    __shared__ double wsum[8];
    __shared__ int nonempty;
    if (t == 0) nonempty = 0;
    __syncthreads();

    // stage: thread t owns (row = t>>1, 8-col chunk q = (t&1)*8)
    {
        const int row = t >> 1;
        const int q   = (t & 1) << 3;
        const int4 rv = *(const int4*)(f + (img << 16) + (row << 8) + j0 + q);
        const short* sv = (const short*)&rv;
        bool ne = false;
#pragma unroll
        for (int j = 0; j < 8; ++j) {
            const int v = sv[j];
            ne = ne || (v != -CAPS);
            float g = (float)v;
            if (v == CAPS)  g =  1.0e6f;
            if (v == -CAPS) g = -1.0e6f;
            sf[row][q + j] = g;
        }
        if (ne) nonempty = 1;             // benign race, all write 1
    }

    // pred prefetch: 8 independent loads issued while LDS fills
    const int c  = t & 15;                // own column within tile
    const int r0 = (t >> 4) << 3;         // own 8-row band
    float pf[8];
#pragma unroll
    for (int ii = 0; ii < 8; ++ii)
        pf[ii] = pred[(img << 16) + ((r0 + ii) << 8) + j0 + c];

    __syncthreads();
    const int flag = nonempty;            // exact: mask.sum() != 0

    // phase B: window-bounded exact min-plus, 8 pixels per thread
    double acc = 0.0;
#pragma unroll
    for (int ii = 0; ii < 8; ++ii) {
        const int i = r0 + ii;
        const float fv = sf[i][c];
        const bool  m  = fv > 0.0f;       // sign(f) = pixel polarity
        const float sgn = m ? 1.0f : -1.0f;
        const float gi = fabsf(fv);
        const int  gii = (int)gi;
        int lo = i - gii; lo = lo > 0 ? lo : 0;
        int hi = i + gii; hi = hi < (H - 1) ? hi : (H - 1);

        float dm = 3.0e38f;
        float dk = (float)(i - lo);
        for (int k = lo; k <= hi; ++k) {
            const float g = fmaxf(sgn * sf[k][c], 0.0f);  // needed polarity
            dm = fminf(dm, g * g + dk * dk);
            dk -= 1.0f;
        }

        float d = m ? sqrtf(dm) : -sqrtf(dm);
        if (!flag) d = 0.0f;
        const float sig = 1.0f / (1.0f + expf(-pf[ii]));
        acc += (double)sig * (double)d;
    }

    // wave reduce (double, fixed order), 8 wave sums -> atomic finalize
#pragma unroll
    for (int off = 32; off > 0; off >>= 1) acc += __shfl_down(acc, off, 64);
    if (lane == 0) wsum[wid] = acc;
    __syncthreads();
    if (t == 0) {
        double s = 0.0;
#pragma unroll
        for (int w = 0; w < 8; ++w) s += wsum[w];
        atomicAdd(out, (float)(s * (1.0 / (double)(NIMG * NPIX))));
    }
}

extern "C" void kernel_launch(void* const* d_in, const int* in_sizes, int n_in,
                              void* d_out, int out_size, void* d_ws, size_t ws_size,
                              hipStream_t stream) {
    const float* pred = (const float*)d_in[0];
    const int*   tgt  = (const int*)d_in[1];
    float* out = (float*)d_out;

    short* fbuf = (short*)d_ws;           // 3,145,728 B intermediate

    edt_rows_kernel<<<384, 256, 0, stream>>>(tgt, fbuf, out);
    edt_cols_kernel<<<NBLK2, 512, 0, stream>>>(fbuf, pred, out);
}